// Round 10
// baseline (2059.794 us; speedup 1.0000x reference)
//
#include <hip/hip_runtime.h>
#include <cmath>

namespace {
constexpr int B_ = 16, T_ = 512, P_ = 256, E_ = 128, NB_ = 4, K_ = 4;

__device__ __forceinline__ float rcpf(float x) { return __builtin_amdgcn_rcpf(x); }
__device__ __forceinline__ float fast_tanh(float x) {
    float a = fabsf(x);
    float t = __expf(-2.0f * a);
    float r = 1.0f - 2.0f * t * rcpf(1.0f + t);
    return copysignf(r, x);
}
// sum over the 4 kq groups (lanes l, l^16, l^32, l^48)
__device__ __forceinline__ float redkq(float v) {
    v += __shfl_xor(v, 16);
    v += __shfl_xor(v, 32);
    return v;
}
__device__ __forceinline__ float sel4(int kq, float a, float b, float c, float d) {
    const float t0 = (kq & 1) ? b : a;
    const float t1 = (kq & 1) ? d : c;
    return (kq & 2) ? t1 : t0;
}
}

// R9 skeleton (e-pair layout, hist-deferred out, proven math) with LEVEL
// SCHEDULING: lev[j] = 1 + max{lev[i]: i<j, |dd|<=8} (block-uniform). Same-
// level bots are pairwise non-overlapping, so each level runs like the proven
// fast path: batched s1 -> ONE barrier -> per-bot matvec (8 wave-uniform b128,
// exact R9-slow fma order) -> s2 -> disjoint scatter. Barriers = nlev + 1.
// Corrections via coefm (0 for non-overlap; sv2 zero-init => exact no-op).
__global__ __launch_bounds__(256, 1)
void swarm_ring_kernel(const float* __restrict__ x,            // (B,T,8)
                       const float* __restrict__ W_in,         // (8,E)
                       const float* __restrict__ b_in,         // (E)
                       const float* __restrict__ W_out,        // (E,8)
                       const float* __restrict__ b_out,        // (8)
                       const float* __restrict__ W_p,          // (E,E)
                       const float* __restrict__ b_p,          // (E)
                       const float* __restrict__ ptr_dest,     // (NB,P)
                       const float* __restrict__ jump_W,       // (NB,E)
                       const float* __restrict__ jump_b,       // (NB)
                       const float* __restrict__ ctx_strength, // (NB)
                       const float* __restrict__ phase_bias,   // (NB,E)
                       const float* __restrict__ pointer_init, // (NB,B)
                       float* __restrict__ out)                // (B,T,8)
{
    __shared__ alignas(16) float ring[P_ * E_];     // 128 KiB
    __shared__ alignas(16) float s1p[NB_ * E_];     // per-bot s1 planes
    __shared__ alignas(16) float red[16];           // per-wave jump partials
    __shared__ alignas(16) float hist[16][132];     // ssum history ring
    __shared__ alignas(16) float wout_s[8][132];    // 0.25 * W_out^T

    const int tid = threadIdx.x;
    const int b   = blockIdx.x;
    const int w   = tid >> 6;
    const int l   = tid & 63;
    const int sub = l & 15;
    const int kq  = l >> 4;                         // 0..3
    const int e0  = ((w << 4) | sub) << 1;          // owned e-pair: e0, e0+1

    for (int k4 = tid; k4 < P_ * E_ / 4; k4 += 256)
        ((float4*)ring)[k4] = make_float4(0.f, 0.f, 0.f, 0.f);
    for (int idx = tid; idx < 8 * E_; idx += 256) {
        const int m = idx >> 7, ee = idx & 127;
        wout_s[m][ee] = W_out[ee * 8 + m] * 0.25f;
    }

    float2 wp2[32];                                 // W_p[32*kq+kk][e0..e0+1]
    #pragma unroll
    for (int kk = 0; kk < 32; ++kk)
        wp2[kk] = *(const float2*)(W_p + (kq * 32 + kk) * E_ + e0);

    const float2 bin2 = *(const float2*)(b_in + e0);
    const float2 bp2  = *(const float2*)(b_p + e0);
    const float  bout_m = b_out[tid & 7];

    float2 pb2[NB_], jw2[NB_], hid2[NB_];
    float  sigc[NB_], jb_r[NB_], ptrv[NB_];
    #pragma unroll
    for (int i = 0; i < NB_; ++i) {
        const float2 pb = *(const float2*)(phase_bias + i * E_ + e0);
        pb2[i] = make_float2(0.1f * pb.x, 0.1f * pb.y);
        jw2[i] = *(const float2*)(jump_W + i * E_ + e0);
        sigc[i] = 1.0f / (1.0f + __expf(-ctx_strength[i]));
        jb_r[i] = jump_b[i];
        hid2[i] = make_float2(0.f, 0.f);
        ptrv[i] = pointer_init[i * B_ + b];
    }

    const float* xb = x + (size_t)b * T_ * 8;
    float xt[8];
    {
        float4 a0 = ((const float4*)xb)[0], a1 = ((const float4*)xb)[1];
        xt[0]=a0.x; xt[1]=a0.y; xt[2]=a0.z; xt[3]=a0.w;
        xt[4]=a1.x; xt[5]=a1.y; xt[6]=a1.z; xt[7]=a1.w;
    }

    const float Cw1 = 0.8824969f, Cw2 = 0.60653066f, Cw3 = 0.32465247f, Cw4 = 0.13533528f;
    const float Dw1 = 0.7788008f, Dw2 = 0.36787944f, Dw3 = 0.105399225f, Dw4 = 0.018315639f;

    __syncthreads();

    for (int t = 0; t < T_; ++t) {
        // ---- geometry, softmax weights, jump-target prefetch (proven math)
        int   baseA[NB_];
        float fA[NB_], psinv[NB_], jt[NB_], wgt[NB_][9];
        #pragma unroll
        for (int i = 0; i < NB_; ++i) {
            const float p = ptrv[i];
            const int base = (int)p;
            baseA[i] = base;
            jt[i] = ptr_dest[i * P_ + base];
            const float f = p - (float)base;
            fA[i] = f;
            const float r  = __expf(0.25f * f);
            const float r2 = r * r, r3 = r2 * r, r4 = r2 * r2;
            const float ri = rcpf(r), ri2 = ri * ri, ri3 = ri2 * ri, ri4 = ri2 * ri2;
            const float p0 = Cw4*ri4, p1 = Cw3*ri3, p2 = Cw2*ri2, p3 = Cw1*ri, p4 = 1.0f,
                        p5 = Cw1*r,  p6 = Cw2*r2,  p7 = Cw3*r3,  p8 = Cw4*r4;
            const float sum = ((p0+p1)+(p2+p3)) + ((p4+p5)+(p6+p7)) + p8;
            const float inv = rcpf(sum);
            psinv[i] = inv;
            wgt[i][0]=p0*inv; wgt[i][1]=p1*inv; wgt[i][2]=p2*inv; wgt[i][3]=p3*inv;
            wgt[i][4]=p4*inv; wgt[i][5]=p5*inv; wgt[i][6]=p6*inv; wgt[i][7]=p7*inv;
            wgt[i][8]=p8*inv;
        }

        // ---- overlap DAG -> levels (block-uniform)
        int ddm[NB_][NB_];
        int lev[NB_];
        lev[0] = 0;
        #pragma unroll
        for (int j = 1; j < NB_; ++j) {
            int mx = -1;
            #pragma unroll
            for (int i = 0; i < j; ++i) {
                const int dd = ((baseA[j] - baseA[i] + 128) & 255) - 128;
                ddm[j][i] = dd;
                if (dd >= -8 && dd <= 8 && lev[i] > mx) mx = lev[i];
            }
            lev[j] = mx + 1;
        }
        const int nlev = 1 + ((lev[1] > lev[0] ? lev[1] : lev[0]) > (lev[2] > lev[3] ? lev[2] : lev[3])
                              ? (lev[1] > lev[0] ? lev[1] : lev[0])
                              : (lev[2] > lev[3] ? lev[2] : lev[3]));

        // ---- gathers: rows kq, kq+4 (+8 on kq0), b64; combine across kq
        float  ws0[NB_], ws1[NB_];
        float2 ctxp2[NB_];
        #pragma unroll
        for (int i = 0; i < NB_; ++i) {
            ws0[i] = sel4(kq, wgt[i][0], wgt[i][1], wgt[i][2], wgt[i][3]);
            ws1[i] = sel4(kq, wgt[i][4], wgt[i][5], wgt[i][6], wgt[i][7]);
            const int r0 = (baseA[i] + kq - K_) & (P_ - 1);
            const int r1 = (baseA[i] + kq + 4 - K_) & (P_ - 1);
            const float2 g0 = *(const float2*)(ring + r0 * E_ + e0);
            const float2 g1 = *(const float2*)(ring + r1 * E_ + e0);
            float cx = fmaf(ws1[i], g1.x, ws0[i] * g0.x);
            float cy = fmaf(ws1[i], g1.y, ws0[i] * g0.y);
            if (kq == 0) {
                const int r2 = (baseA[i] + 8 - K_) & (P_ - 1);
                const float2 g2 = *(const float2*)(ring + r2 * E_ + e0);
                cx = fmaf(wgt[i][8], g2.x, cx);
                cy = fmaf(wgt[i][8], g2.y, cy);
            }
            ctxp2[i] = make_float2(redkq(cx), redkq(cy));
        }

        // ---- cross-bot correction coefficients (0 for non-overlap pairs)
        float coefm[NB_][NB_];
        #pragma unroll
        for (int j = 1; j < NB_; ++j) {
            #pragma unroll
            for (int i = 0; i < j; ++i) {
                const int dd = ddm[j][i];
                float c = 0.f;
                if (dd >= -8 && dd <= 8) {
                    const float A = (float)dd - fA[i];
                    const float s  = __expf(-0.25f * (A - fA[j]));
                    const float G  = __expf(0.125f * (fA[i] * fA[i] - A * A));
                    const float s2p = s * s, s3p = s2p * s, s4p = s2p * s2p;
                    const float si = rcpf(s), si2 = si * si, si3 = si2 * si, si4 = si2 * si2;
                    float acc = 0.f;
                    acc += (dd >= 0)              ? Dw4 * si4 : 0.f;
                    acc += (dd >= -1 && dd <= 7)  ? Dw3 * si3 : 0.f;
                    acc += (dd >= -2 && dd <= 6)  ? Dw2 * si2 : 0.f;
                    acc += (dd >= -3 && dd <= 5)  ? Dw1 * si  : 0.f;
                    acc += (dd >= -4 && dd <= 4)  ? 1.0f      : 0.f;
                    acc += (dd >= -5 && dd <= 3)  ? Dw1 * s   : 0.f;
                    acc += (dd >= -6 && dd <= 2)  ? Dw2 * s2p : 0.f;
                    acc += (dd >= -7 && dd <= 1)  ? Dw3 * s3p : 0.f;
                    acc += (dd <= 0)              ? Dw4 * s4p : 0.f;
                    c = psinv[i] * psinv[j] * G * acc;
                }
                coefm[j][i] = c;
            }
        }

        // ---- inp = x_t @ W_in + b_in
        float2 inp2 = bin2;
        #pragma unroll
        for (int k = 0; k < 8; ++k) {
            const float2 wk = *(const float2*)(W_in + k * E_ + e0);
            inp2.x = fmaf(xt[k], wk.x, inp2.x);
            inp2.y = fmaf(xt[k], wk.y, inp2.y);
        }

        float xtn[8];
        if (t + 1 < T_) {
            float4 a0 = ((const float4*)(xb + (t + 1) * 8))[0];
            float4 a1 = ((const float4*)(xb + (t + 1) * 8))[1];
            xtn[0]=a0.x; xtn[1]=a0.y; xtn[2]=a0.z; xtn[3]=a0.w;
            xtn[4]=a1.x; xtn[5]=a1.y; xtn[6]=a1.z; xtn[7]=a1.w;
        } else {
            #pragma unroll
            for (int k = 0; k < 8; ++k) xtn[k] = 0.f;
        }

        // ---- level-scheduled bot execution
        float2 sv2[NB_];
        #pragma unroll
        for (int j = 0; j < NB_; ++j) sv2[j] = make_float2(0.f, 0.f);

        for (int L = 0; L < nlev; ++L) {            // uniform runtime bound <=4
            // phase A: s1 for level-L bots -> per-bot LDS plane
            #pragma unroll
            for (int j = 0; j < NB_; ++j) {
                if (lev[j] != L) continue;           // uniform branch
                float2 ctx = ctxp2[j];
                #pragma unroll
                for (int i = 0; i < j; ++i) {        // coef=0 for non-overlap
                    ctx.x = fmaf(coefm[j][i], sv2[i].x, ctx.x);
                    ctx.y = fmaf(coefm[j][i], sv2[i].y, ctx.y);
                }
                float2 s1;
                s1.x = fast_tanh(fmaf(sigc[j], ctx.x, inp2.x + pb2[j].x + hid2[j].x));
                s1.y = fast_tanh(fmaf(sigc[j], ctx.y, inp2.y + pb2[j].y + hid2[j].y));
                if (kq == 0) *(float2*)(s1p + j * E_ + e0) = s1;   // conflict-free b64
            }
            __syncthreads();                         // level barrier

            // phase B: matvec + s2 + scatter for level-L bots
            #pragma unroll
            for (int j = 0; j < NB_; ++j) {
                if (lev[j] != L) continue;           // uniform branch
                const float4* sp = (const float4*)(s1p + j * E_) + kq * 8;
                float ax = 0.f, ay = 0.f;
                #pragma unroll
                for (int kk = 0; kk < 8; ++kk) {
                    const float4 sq = sp[kk];
                    const float2 wa = wp2[4 * kk + 0], wb = wp2[4 * kk + 1];
                    const float2 wc = wp2[4 * kk + 2], wd = wp2[4 * kk + 3];
                    ax = fmaf(sq.x, wa.x, ax); ay = fmaf(sq.x, wa.y, ay);
                    ax = fmaf(sq.y, wb.x, ax); ay = fmaf(sq.y, wb.y, ay);
                    ax = fmaf(sq.z, wc.x, ax); ay = fmaf(sq.z, wc.y, ay);
                    ax = fmaf(sq.w, wd.x, ax); ay = fmaf(sq.w, wd.y, ay);
                }
                float2 s2;
                s2.x = fast_tanh(redkq(ax) + bp2.x);
                s2.y = fast_tanh(redkq(ay) + bp2.y);
                sv2[j] = s2; hid2[j] = s2;

                // disjoint b64 scatter: lane owns rows kq, kq+4 (+8 on kq0)
                const int r0 = (baseA[j] + kq - K_) & (P_ - 1);
                float2* q0 = (float2*)(ring + r0 * E_ + e0);
                float2 v0 = *q0;
                v0.x = fmaf(ws0[j], s2.x, v0.x); v0.y = fmaf(ws0[j], s2.y, v0.y);
                *q0 = v0;
                const int r1 = (baseA[j] + kq + 4 - K_) & (P_ - 1);
                float2* q1 = (float2*)(ring + r1 * E_ + e0);
                float2 v1 = *q1;
                v1.x = fmaf(ws1[j], s2.x, v1.x); v1.y = fmaf(ws1[j], s2.y, v1.y);
                *q1 = v1;
                if (kq == 0) {
                    const int r2 = (baseA[j] + 8 - K_) & (P_ - 1);
                    float2* q2 = (float2*)(ring + r2 * E_ + e0);
                    float2 v2 = *q2;
                    v2.x = fmaf(wgt[j][8], s2.x, v2.x); v2.y = fmaf(wgt[j][8], s2.y, v2.y);
                    *q2 = v2;
                }
            }
        }

        // ---- jump dots: per-lane pair dot, reduce over the wave's 16 pairs
        {
            float vj0 = fmaf(sv2[0].y, jw2[0].y, sv2[0].x * jw2[0].x);
            float vj1 = fmaf(sv2[1].y, jw2[1].y, sv2[1].x * jw2[1].x);
            float vj2 = fmaf(sv2[2].y, jw2[2].y, sv2[2].x * jw2[2].x);
            float vj3 = fmaf(sv2[3].y, jw2[3].y, sv2[3].x * jw2[3].x);
            #pragma unroll
            for (int off = 1; off < 16; off <<= 1) {
                vj0 += __shfl_xor(vj0, off);
                vj1 += __shfl_xor(vj1, off);
                vj2 += __shfl_xor(vj2, off);
                vj3 += __shfl_xor(vj3, off);
            }
            if (l == 0)
                ((float4*)red)[w] = make_float4(vj0, vj1, vj2, vj3);
        }

        // ---- ssum -> history ring (kq0 lanes, b64)
        {
            float2 ssum2;
            ssum2.x = (sv2[0].x + sv2[1].x) + (sv2[2].x + sv2[3].x);
            ssum2.y = (sv2[0].y + sv2[1].y) + (sv2[2].y + sv2[3].y);
            if (kq == 0) *(float2*)(&hist[t & 15][e0]) = ssum2;
        }

        __syncthreads();                             // scatters + red + hist visible

        {
            const float4 r0 = ((const float4*)red)[0];
            const float4 r1 = ((const float4*)red)[1];
            const float4 r2 = ((const float4*)red)[2];
            const float4 r3 = ((const float4*)red)[3];
            const float zz[4] = {
                ((r0.x + r1.x) + (r2.x + r3.x)) + jb_r[0],
                ((r0.y + r1.y) + (r2.y + r3.y)) + jb_r[1],
                ((r0.z + r1.z) + (r2.z + r3.z)) + jb_r[2],
                ((r0.w + r1.w) + (r2.w + r3.w)) + jb_r[3]};
            #pragma unroll
            for (int i = 0; i < NB_; ++i) {
                float np;
                if (zz[i] > 0.0f) np = jt[i];
                else { np = ptrv[i] + 1.0f; if (np >= 256.0f) np -= 256.0f; }
                ptrv[i] = np;
            }
        }

        // ---- every 8th step: 64 threads compute the deferred out dots
        if ((t & 7) == 7 && tid < 64) {
            const int tt = tid >> 3;
            const int m  = tid & 7;
            const float* hrow = hist[(t - 7 + tt) & 15];
            const float* wrow = wout_s[m];
            float acc = 0.f;
            #pragma unroll
            for (int q = 0; q < 32; ++q) {
                const float4 h4 = ((const float4*)hrow)[q];
                const float4 w4 = ((const float4*)wrow)[q];
                acc += ((h4.x * w4.x + h4.y * w4.y) + (h4.z * w4.z + h4.w * w4.w));
            }
            out[((size_t)b * T_ + (t - 7 + tt)) * 8 + m] = acc + bout_m;
        }

        #pragma unroll
        for (int k = 0; k < 8; ++k) xt[k] = xtn[k];
    }
}

extern "C" void kernel_launch(void* const* d_in, const int* in_sizes, int n_in,
                              void* d_out, int out_size, void* d_ws, size_t ws_size,
                              hipStream_t stream) {
    (void)in_sizes; (void)n_in; (void)out_size; (void)d_ws; (void)ws_size;
    swarm_ring_kernel<<<dim3(B_), dim3(256), 0, stream>>>(
        (const float*)d_in[0],  (const float*)d_in[1],  (const float*)d_in[2],
        (const float*)d_in[3],  (const float*)d_in[4],  (const float*)d_in[5],
        (const float*)d_in[6],  (const float*)d_in[7],  (const float*)d_in[8],
        (const float*)d_in[9],  (const float*)d_in[10], (const float*)d_in[11],
        (const float*)d_in[12], (float*)d_out);
}